// Round 11
// baseline (446.559 us; speedup 1.0000x reference)
//
#include <hip/hip_runtime.h>
#include <hip/hip_bf16.h>

typedef __bf16 bf16;
typedef __bf16 bf16x4 __attribute__((ext_vector_type(4)));
typedef __bf16 bf16x8 __attribute__((ext_vector_type(8)));
typedef float f32x4 __attribute__((ext_vector_type(4)));

__device__ __forceinline__ float fast_exp2(float x) {
#if __has_builtin(__builtin_amdgcn_exp2f)
    return __builtin_amdgcn_exp2f(x);
#else
    return exp2f(x);
#endif
}

// fast natural log via v_log_f32 -- log1pf() lowers to the slow OCML path
// (~260 VALU inst/elem measured in r6's delta-GEMM; fix was -42 us).
__device__ __forceinline__ float fast_log(float x) {
#if __has_builtin(__builtin_amdgcn_logf)
    return __builtin_amdgcn_logf(x) * 0.6931471805599453f;
#else
    return __logf(x);
#endif
}

// async global->LDS, 16B per lane. lds base must be wave-uniform; the HW
// writes lds + lane*16; the GLOBAL address is per-lane. (m97 pattern)
__device__ __forceinline__ void gload16(bf16* lds, const bf16* g) {
    __builtin_amdgcn_global_load_lds(
        (const __attribute__((address_space(1))) void*)g,
        (__attribute__((address_space(3))) void*)lds,
        16, 0, 0);
}

// ---------------------------------------------------------------------------
// f32 -> bf16 vectorized cast (8 elems / thread)
// ---------------------------------------------------------------------------
__device__ __forceinline__ bf16x8 cvt8(const float* p) {
    float4 a = *(const float4*)p;
    float4 b = *(const float4*)(p + 4);
    bf16x8 r;
    r[0] = (bf16)a.x; r[1] = (bf16)a.y; r[2] = (bf16)a.z; r[3] = (bf16)a.w;
    r[4] = (bf16)b.x; r[5] = (bf16)b.y; r[6] = (bf16)b.z; r[7] = (bf16)b.w;
    return r;
}

__global__ __launch_bounds__(256) void cvt_bf16(
    const float* __restrict__ in, bf16* __restrict__ out, int n8)
{
    int i = blockIdx.x * 256 + threadIdx.x;
    if (i < n8)
        *(bf16x8*)(out + (size_t)i * 8) = cvt8(in + (size_t)i * 8);
}

// one merged pass for all start-of-graph conversions:
// x (1048576 x8), W_in lo (262144), W_in hi (262144), W_x (24576), W_dt (16384)
__global__ __launch_bounds__(256) void cvt_all(
    const float* __restrict__ x,  const float* __restrict__ W_in,
    const float* __restrict__ W_x, const float* __restrict__ W_dt,
    bf16* __restrict__ xb, bf16* __restrict__ Wlo, bf16* __restrict__ Whi,
    bf16* __restrict__ Wxb, bf16* __restrict__ Wdtb)
{
    int i = blockIdx.x * 256 + threadIdx.x;
    if (i < 1048576) {
        *(bf16x8*)(xb + (size_t)i * 8) = cvt8(x + (size_t)i * 8);
    } else if (i < 1310720) {
        int j = i - 1048576;
        *(bf16x8*)(Wlo + (size_t)j * 8) = cvt8(W_in + (size_t)j * 8);
    } else if (i < 1572864) {
        int j = i - 1310720;
        *(bf16x8*)(Whi + (size_t)j * 8) = cvt8(W_in + 2097152 + (size_t)j * 8);
    } else if (i < 1597440) {
        int j = i - 1572864;
        *(bf16x8*)(Wxb + (size_t)j * 8) = cvt8(W_x + (size_t)j * 8);
    } else if (i < 1613824) {
        int j = i - 1597440;
        *(bf16x8*)(Wdtb + (size_t)j * 8) = cvt8(W_dt + (size_t)j * 8);
    }
}

// ---------------------------------------------------------------------------
// 256x256 8-phase GEMM (m198-style linear-LDS variant, T3+T4+T5):
// C[M x N] = A[M x K] * B[N x K]^T, full 256-tiles only (M%256==0, N%256==0,
// K%128==0).  8 waves (2Mx4N), 512 threads, BK=64, LDS = 2buf x (A+B 32KB)
// = 128KB -> 1 block/CU.  Per K-tile: 4 phases, each {stage 1 half-tile of
// a FUTURE tile (2 gload16) || ds_read quadrant || 16 MFMA}; counted
// s_waitcnt vmcnt(2) + raw s_barrier at tile entry; barrier at tile exit.
// Loads stay in flight across barriers (never vmcnt(0) in the loop).
// Tail stages are source-clamped so vmcnt counts stay uniform.
// EPI==0: plain store   EPI==2: out = gmul[row,col] * silu(acc)
// K-accumulation order identical to gemm_bt (absmax-neutral).
// ---------------------------------------------------------------------------
template <int EPI, typename TC>
__global__ __launch_bounds__(512, 2) void gemm256(
    const bf16* __restrict__ A, int lda,
    const bf16* __restrict__ B, int ldb,
    TC* __restrict__ C, int ldc,
    int K, const bf16* __restrict__ gmul)
{
    __shared__ bf16 sA[2][256 * 64];
    __shared__ bf16 sB[2][256 * 64];

    const int tid  = threadIdx.x;
    const int lane = tid & 63;
    const int wave = tid >> 6;      // 0..7
    const int quad = lane >> 4;
    const int l16  = lane & 15;
    const int wr   = wave >> 2;     // 0..1  (M half)
    const int wc   = wave & 3;      // 0..3  (N quarter)
    const int bm   = blockIdx.x << 8;
    const int bn   = blockIdx.y << 8;

    // staging map: unit u in {0:A-half0, 1:A-half1, 2:B-half0, 3:B-half1};
    // each wave covers 16 rows of the 128-row half via 2 gload16 (8 rows ea).
    const int srow = wave * 16 + (lane >> 3);   // row within half (+0 / +8)
    const int scol = (lane & 7) * 8;            // col (bf16 elems)

    f32x4 acc[8][4] = {};

    const int KT = K >> 6;

#define STAGE(pb, u, kt) do {                                              \
    int kc_ = (kt) * 64; if (kc_ > K - 64) kc_ = K - 64;                   \
    const int half_ = (u) & 1;                                             \
    bf16* dst_ = (((u) < 2) ? sA[pb] : sB[pb]) + (half_ * 128 + wave * 16) * 64; \
    const bf16* src_ = ((u) < 2)                                           \
        ? A + (size_t)(bm + half_ * 128 + srow) * lda + kc_ + scol         \
        : B + (size_t)(bn + half_ * 128 + srow) * ldb + kc_ + scol;        \
    const int ld_ = ((u) < 2) ? lda : ldb;                                 \
    gload16(dst_, src_);                                                   \
    gload16(dst_ + 8 * 64, src_ + (size_t)8 * ld_);                        \
} while (0)

    // prologue: tile 0 -> buf0 (8 loads/thread-wave)
    STAGE(0, 0, 0); STAGE(0, 1, 0); STAGE(0, 2, 0); STAGE(0, 3, 0);

    for (int it = 0; it < KT / 2; ++it) {
#pragma unroll
        for (int ph = 0; ph < 8; ++ph) {
            const int p = ph >> 2;          // buffer being read
            const int q = ph & 3;           // phase-within-tile = quadrant
            // phases 0-3 stage tile 2it+1 -> buf1; 4-7 stage 2it+2 -> buf0
            STAGE(p ^ 1, q, 2 * it + 1 + p);
            if (q == 0) {
                // drain the tile we are about to read (2 newest stay in flight)
                asm volatile("s_waitcnt vmcnt(2)" ::: "memory");
                __builtin_amdgcn_s_barrier();
            }
            const int qm = q >> 1, qn = q & 1;
            bf16x8 af[4][2], bq[2][2];
            const bf16* Ar = sA[p] + (wr * 128 + qm * 64 + l16) * 64 + quad * 8;
            const bf16* Br = sB[p] + (wc * 64 + qn * 32 + l16) * 64 + quad * 8;
#pragma unroll
            for (int fm = 0; fm < 4; ++fm)
#pragma unroll
                for (int ks = 0; ks < 2; ++ks)
                    af[fm][ks] = *(const bf16x8*)(Ar + fm * 16 * 64 + ks * 32);
#pragma unroll
            for (int fn = 0; fn < 2; ++fn)
#pragma unroll
                for (int ks = 0; ks < 2; ++ks)
                    bq[fn][ks] = *(const bf16x8*)(Br + fn * 16 * 64 + ks * 32);
            __builtin_amdgcn_s_setprio(1);
#pragma unroll
            for (int fm = 0; fm < 4; ++fm)
#pragma unroll
                for (int fn = 0; fn < 2; ++fn)
#pragma unroll
                    for (int ks = 0; ks < 2; ++ks)
                        acc[qm * 4 + fm][qn * 2 + fn] =
                            __builtin_amdgcn_mfma_f32_16x16x32_bf16(
                                af[fm][ks], bq[fn][ks],
                                acc[qm * 4 + fm][qn * 2 + fn], 0, 0, 0);
            __builtin_amdgcn_s_setprio(0);
            if (q == 3) __builtin_amdgcn_s_barrier();  // buffer handoff
        }
    }
#undef STAGE

    // epilogue: C/D layout row = quad*4 + r, col = l16 (m89-verified)
#pragma unroll
    for (int mi = 0; mi < 8; ++mi) {
        const int row = bm + wr * 128 + mi * 16 + quad * 4;
#pragma unroll
        for (int ni = 0; ni < 4; ++ni) {
            const int col = bn + wc * 64 + ni * 16 + l16;
#pragma unroll
            for (int r = 0; r < 4; ++r) {
                float v = acc[mi][ni][r];
                if (EPI == 2) {
                    float g = v / (1.f + __expf(-v));   // silu(z)
                    v = (float)gmul[(size_t)(row + r) * ldc + col] * g;
                }
                C[(size_t)(row + r) * ldc + col] = (TC)v;
            }
        }
    }
}

// ---------------------------------------------------------------------------
// C[M x N] = A[M x K] * B[N x K]^T   (A,B bf16; f32 accum; TC out)
// m97 structure, BK=64 (used for the small/odd-shape GEMMs: N=96 splitK,
// K=64 delta, N=1024 out).
// EPI==0: plain   EPI==1: softplus(acc + bias_f32[col])
// EPI==2: out = gmul_bf16[row,col] * silu(acc)
// grid.z splits K: block z computes K range [z*K,(z+1)*K) -> C + z*zstride.
// Requires K % 64 == 0.
// ---------------------------------------------------------------------------
template <int EPI, typename TC>
__global__ __launch_bounds__(256, 2) void gemm_bt(
    const bf16* __restrict__ A, int lda,
    const bf16* __restrict__ B, int ldb,
    TC* __restrict__ C, int ldc,
    int K, int Neff, const float* __restrict__ bias,
    const bf16* __restrict__ gmul, size_t zstride)
{
    __shared__ bf16 As0[128 * 32];
    __shared__ bf16 As1[128 * 32];
    __shared__ bf16 Bs0[128 * 32];
    __shared__ bf16 Bs1[128 * 32];

    const int tid  = threadIdx.x;
    const int lane = tid & 63;
    const int wave = tid >> 6;
    const int quad = lane >> 4;
    const int l16  = lane & 15;
    const int wm   = (wave >> 1) << 6;
    const int wn   = (wave & 1) << 6;
    const int bm   = blockIdx.x << 7;
    const int bn   = blockIdx.y << 7;
    const int kb   = blockIdx.z * K;

    const int srow = (wave << 4) + (lane >> 2);
    const int scol = (lane & 3) << 3;

    const bf16* Ag0 = A + (size_t)(bm + srow) * lda + kb + scol;
    const bf16* Ag1 = Ag0 + (size_t)lda * 64;
    int br0 = bn + srow;      br0 = br0 < Neff ? br0 : Neff - 1;
    int br1 = bn + srow + 64; br1 = br1 < Neff ? br1 : Neff - 1;
    const bf16* Bg0 = B + (size_t)br0 * ldb + kb + scol;
    const bf16* Bg1 = B + (size_t)br1 * ldb + kb + scol;

    const int wofs = wave * 512;            // wave-uniform LDS base offset

    f32x4 acc[4][4] = {};

    for (int k0 = 0; k0 < K; k0 += 64) {
        if (k0) __syncthreads();            // protect LDS from overwrite
        gload16(As0 + wofs,        Ag0 + k0);
        gload16(As0 + 2048 + wofs, Ag1 + k0);
        gload16(Bs0 + wofs,        Bg0 + k0);
        gload16(Bs0 + 2048 + wofs, Bg1 + k0);
        gload16(As1 + wofs,        Ag0 + k0 + 32);
        gload16(As1 + 2048 + wofs, Ag1 + k0 + 32);
        gload16(Bs1 + wofs,        Bg0 + k0 + 32);
        gload16(Bs1 + 2048 + wofs, Bg1 + k0 + 32);
        __syncthreads();                    // drains vmcnt before barrier

#pragma unroll
        for (int kk = 0; kk < 2; ++kk) {
            const bf16* Ak = kk ? As1 : As0;
            const bf16* Bk = kk ? Bs1 : Bs0;
            bf16x8 af[4], bfr[4];
#pragma unroll
            for (int i = 0; i < 4; ++i) {
                af[i]  = *(const bf16x8*)(Ak + (wm + i * 16 + l16) * 32 + quad * 8);
                bfr[i] = *(const bf16x8*)(Bk + (wn + i * 16 + l16) * 32 + quad * 8);
            }
#pragma unroll
            for (int mi = 0; mi < 4; ++mi)
#pragma unroll
                for (int ni = 0; ni < 4; ++ni)
                    acc[mi][ni] = __builtin_amdgcn_mfma_f32_16x16x32_bf16(
                        af[mi], bfr[ni], acc[mi][ni], 0, 0, 0);
        }
    }

    TC* Cz = C + (size_t)blockIdx.z * zstride;

    // C/D layout: row = quad*4 + r, col = l16  (m89-verified)
#pragma unroll
    for (int mi = 0; mi < 4; ++mi) {
        const int row = bm + wm + mi * 16 + quad * 4;
#pragma unroll
        for (int ni = 0; ni < 4; ++ni) {
            const int col = bn + wn + ni * 16 + l16;
            if (col < Neff) {
                float bc = (EPI == 1) ? bias[col] : 0.f;
#pragma unroll
                for (int r = 0; r < 4; ++r) {
                    float v = acc[mi][ni][r];
                    if (EPI == 1) {
                        v += bc;
                        float sp = fast_log(1.f + __expf(v));
                        v = (v > 15.f) ? v : sp;
                    } else if (EPI == 2) {
                        float g = v / (1.f + __expf(-v));   // silu(z)
                        v = (float)gmul[(size_t)(row + r) * ldc + col] * g;
                    }
                    Cz[(size_t)(row + r) * ldc + col] = (TC)v;
                }
            }
        }
    }
}

// ---------------------------------------------------------------------------
// split-K reduce + dtype split: row-major [8192][96] f32 partials summed
// over 4 z-slices.  Cols 0-63 (dt) -> dtb bf16 (gemm4 MFMA operand);
// cols 64-95 (B,C) -> BCf f32 (scan reads f32 directly).
// ---------------------------------------------------------------------------
__global__ __launch_bounds__(256) void reduce_split(
    const float* __restrict__ P, bf16* __restrict__ dtb,
    float* __restrict__ BCf)
{
    const size_t base = ((size_t)blockIdx.x * 256 + threadIdx.x) * 4;
    f32x4 s = *(const f32x4*)(P + base);
#pragma unroll
    for (int z = 1; z < 4; ++z) {
        f32x4 p = *(const f32x4*)(P + (size_t)z * 786432 + base);
        s[0] += p[0]; s[1] += p[1]; s[2] += p[2]; s[3] += p[3];
    }
    const int row = (int)(base / 96);
    const int col = (int)(base % 96);
    if (col < 64) {
        bf16x4 o;
        o[0] = (bf16)s[0]; o[1] = (bf16)s[1];
        o[2] = (bf16)s[2]; o[3] = (bf16)s[3];
        *(bf16x4*)(dtb + (size_t)row * 64 + col) = o;
    } else {
        *(f32x4*)(BCf + (size_t)row * 32 + (col - 64)) = s;
    }
}

// ---------------------------------------------------------------------------
// causal depthwise conv (k=4, left pad 3) + bias + SiLU: xh bf16 -> xc bf16
// t-tiled: each thread produces 8 consecutive t for 8 channels.
// ---------------------------------------------------------------------------
__global__ __launch_bounds__(256) void conv_kernel(
    const bf16* __restrict__ xh, const float* __restrict__ cw,
    const float* __restrict__ cb, bf16* __restrict__ xc)
{
    const int t0 = blockIdx.x << 3;          // 0..2040
    const int b  = blockIdx.y;
    const int d  = threadIdx.x * 8;

    float4 wv[8];           // wv[i] = taps 0..3 of channel d+i
#pragma unroll
    for (int i = 0; i < 8; ++i)
        wv[i] = *(const float4*)(cw + (d + i) * 4);

    float4 cb0 = *(const float4*)(cb + d);
    float4 cb1 = *(const float4*)(cb + d + 4);

    float acc[8][8];
#pragma unroll
    for (int k = 0; k < 8; ++k) {
        acc[k][0] = cb0.x; acc[k][1] = cb0.y; acc[k][2] = cb0.z; acc[k][3] = cb0.w;
        acc[k][4] = cb1.x; acc[k][5] = cb1.y; acc[k][6] = cb1.z; acc[k][7] = cb1.w;
    }

    const bf16* base = xh + ((size_t)b * 2048 + t0) * 2048 + d;

#pragma unroll
    for (int r = 0; r < 11; ++r) {
        const int t_in = t0 - 3 + r;
        if (t_in >= 0) {                     // uniform branch
            bf16x8 v = *(const bf16x8*)(base + (size_t)(r - 3) * 2048);
            float vf[8];
#pragma unroll
            for (int i = 0; i < 8; ++i) vf[i] = (float)v[i];
#pragma unroll
            for (int j = 0; j < 4; ++j) {    // tap j multiplies x[t-3+j]
                const int local = r - j;     // output index t0+local
                if (local >= 0 && local < 8) {
#pragma unroll
                    for (int i = 0; i < 8; ++i) {
                        float w = (j == 0) ? wv[i].x : (j == 1) ? wv[i].y
                                : (j == 2) ? wv[i].z : wv[i].w;
                        acc[local][i] += w * vf[i];
                    }
                }
            }
        }
    }

    bf16* ob = xc + ((size_t)b * 2048 + t0) * 2048 + d;
#pragma unroll
    for (int k = 0; k < 8; ++k) {
        bf16x8 o;
#pragma unroll
        for (int i = 0; i < 8; ++i) {
            float s = acc[k][i];
            o[i] = (bf16)(s / (1.f + __expf(-s)));
        }
        *(bf16x8*)(ob + (size_t)k * 2048) = o;
    }
}

// ---------------------------------------------------------------------------
// Chunk-parallel selective scan, NC=64 chunks x TC=32 t.
// thread = (b, c, d); 16 states in registers; B/C read as f32x4.
// BCf layout: [row][32] f32, idx 0-15 = B[n], 16-31 = C[n].
// Hb: (b, c, d, n) bf16.  sdt: (b, c, d) f32; p2 recomputes A_c.
// ---------------------------------------------------------------------------
__global__ __launch_bounds__(256, 4) void scan_p1(
    const bf16* __restrict__ delta, const float* __restrict__ BCf,
    const float* __restrict__ A_raw, const bf16* __restrict__ xc,
    bf16* __restrict__ Hb, float* __restrict__ sdtb)
{
    const int d = (blockIdx.x << 8) + threadIdx.x;
    const int b = blockIdx.y;
    const int c = blockIdx.z;

    float A2[16];           // A[n] * log2(e)
#pragma unroll
    for (int n = 0; n < 16; ++n)
        A2[n] = -__expf(A_raw[n * 2048 + d]) * 1.44269504f;

    float h[16];
#pragma unroll
    for (int n = 0; n < 16; ++n) h[n] = 0.f;
    float sdt = 0.f;

    const size_t xbase = ((size_t)(b * 2048 + c * 32)) * 2048 + d;
    const bf16* xp = xc + xbase;
    const bf16* dp = delta + xbase;
    const float* bp = BCf + (size_t)(b * 2048 + c * 32) * 32;

    bf16 xr = xp[0], dr = dp[0];
    f32x4 B0 = *(const f32x4*)(bp);
    f32x4 B1 = *(const f32x4*)(bp + 4);
    f32x4 B2 = *(const f32x4*)(bp + 8);
    f32x4 B3 = *(const f32x4*)(bp + 12);

#pragma unroll 4
    for (int t = 0; t < 32; ++t) {
        const float x  = (float)xr;
        const float dt = (float)dr;
        const f32x4 Ba = B0, Bb = B1, Bc = B2, Bd = B3;
        if (t < 31) {
            xr = xp[(size_t)(t + 1) * 2048];
            dr = dp[(size_t)(t + 1) * 2048];
            const float* nb = bp + (size_t)(t + 1) * 32;
            B0 = *(const f32x4*)nb;
            B1 = *(const f32x4*)(nb + 4);
            B2 = *(const f32x4*)(nb + 8);
            B3 = *(const f32x4*)(nb + 12);
        }
        const float dx = dt * x;
        sdt += dt;
#pragma unroll
        for (int n = 0; n < 4; ++n) {
            float e = fast_exp2(dt * A2[n]);
            h[n] = e * h[n] + Ba[n] * dx;
        }
#pragma unroll
        for (int n = 0; n < 4; ++n) {
            float e = fast_exp2(dt * A2[n + 4]);
            h[n + 4] = e * h[n + 4] + Bb[n] * dx;
        }
#pragma unroll
        for (int n = 0; n < 4; ++n) {
            float e = fast_exp2(dt * A2[n + 8]);
            h[n + 8] = e * h[n + 8] + Bc[n] * dx;
        }
#pragma unroll
        for (int n = 0; n < 4; ++n) {
            float e = fast_exp2(dt * A2[n + 12]);
            h[n + 12] = e * h[n + 12] + Bd[n] * dx;
        }
    }

    const size_t hbase = (((size_t)b * 64 + c) * 2048 + d) * 16;
    bf16x8 h0, h1;
#pragma unroll
    for (int n = 0; n < 8; ++n) {
        h0[n] = (bf16)h[n];
        h1[n] = (bf16)h[n + 8];
    }
    *(bf16x8*)(Hb + hbase) = h0;
    *(bf16x8*)(Hb + hbase + 8) = h1;
    sdtb[((size_t)b * 64 + c) * 2048 + d] = sdt;
}

// sequential combine over 64 chunks; recomputes A_c = exp2(A2 * sdt_c).
// thread id = b*32768 + d*16 + n  (H reads/writes coalesced).
__global__ __launch_bounds__(256) void scan_p2(
    bf16* __restrict__ Hb, const float* __restrict__ sdtb,
    const float* __restrict__ A_raw)
{
    const int id  = blockIdx.x * 256 + threadIdx.x;
    const int b   = id >> 15;
    const int rem = id & 32767;
    const int d   = rem >> 4;
    const int n   = rem & 15;

    const float A2 = -__expf(A_raw[n * 2048 + d]) * 1.44269504f;
    const size_t hb = (size_t)b * 64 * 32768 + rem;   // + c*32768
    const size_t sb = (size_t)b * 64 * 2048 + d;      // + c*2048

    float ht = (float)Hb[hb];              // H~_0 = H_0 (already stored)
#pragma unroll 4
    for (int c = 1; c < 64; ++c) {
        float Hv = (float)Hb[hb + (size_t)c * 32768];
        float a  = fast_exp2(A2 * sdtb[sb + (size_t)c * 2048]);
        ht = Hv + a * ht;
        Hb[hb + (size_t)c * 32768] = (bf16)ht;
    }
}

__global__ __launch_bounds__(256, 4) void scan_p3(
    const bf16* __restrict__ delta, const float* __restrict__ BCf,
    const float* __restrict__ A_raw, const float* __restrict__ Dvec,
    const bf16* __restrict__ Hb, const bf16* xc, bf16* ry)
{
    const int d = (blockIdx.x << 8) + threadIdx.x;
    const int b = blockIdx.y;
    const int c = blockIdx.z;

    float A2[16];
#pragma unroll
    for (int n = 0; n < 16; ++n)
        A2[n] = -__expf(A_raw[n * 2048 + d]) * 1.44269504f;
    const float Dd = Dvec[d];

    float h[16];
    if (c > 0) {
        const bf16* Hp = Hb + (((size_t)b * 64 + (c - 1)) * 2048 + d) * 16;
        bf16x8 v0 = *(const bf16x8*)Hp;
        bf16x8 v1 = *(const bf16x8*)(Hp + 8);
#pragma unroll
        for (int n = 0; n < 8; ++n) {
            h[n]     = (float)v0[n];
            h[n + 8] = (float)v1[n];
        }
    } else {
#pragma unroll
        for (int n = 0; n < 16; ++n) h[n] = 0.f;
    }

    const size_t xbase = ((size_t)(b * 2048 + c * 32)) * 2048 + d;
    const bf16* xp = xc + xbase;
    const bf16* dp = delta + xbase;
    const float* bp = BCf + (size_t)(b * 2048 + c * 32) * 32;
    bf16* yp = ry + xbase;

    bf16 xr = xp[0], dr = dp[0];
    f32x4 B0 = *(const f32x4*)(bp);
    f32x4 B1 = *(const f32x4*)(bp + 4);
    f32x4 B2 = *(const f32x4*)(bp + 8);
    f32x4 B3 = *(const f32x4*)(bp + 12);
    f32x4 C0 = *(const f32x4*)(bp + 16);
    f32x4 C1 = *(const f32x4*)(bp + 20);
    f32x4 C2 = *(const f32x4*)(bp + 24);
    f32x4 C3 = *(const f32x4*)(bp + 28);

#pragma unroll 4
    for (int t = 0; t < 32; ++t) {
        const float x  = (float)xr;
        const float dt = (float)dr;
        const f32x4 Ba = B0, Bb = B1, Bc = B2, Bd = B3;
        const f32x4 Ca = C0, Cb = C1, Cc = C2, Cd = C3;
        if (t < 31) {
            xr = xp[(size_t)(t + 1) * 2048];
            dr = dp[(size_t)(t + 1) * 2048];
            const float* nb = bp + (size_t)(t + 1) * 32;
            B0 = *(const f32x4*)nb;
            B1 = *(const f32x4*)(nb + 4);
            B2 = *(const f32x4*)(nb + 8);
            B3 = *(const f32x4*)(nb + 12);
            C0 = *(const f32x4*)(nb + 16);
            C1 = *(const f32x4*)(nb + 20);
            C2 = *(const f32x4*)(nb + 24);
            C3 = *(const f32x4*)(nb + 28);
        }
        const float dx = dt * x;
        float y = Dd * x;
#pragma unroll
        for (int n = 0; n < 4; ++n) {
            float e = fast_exp2(dt * A2[n]);
            h[n] = e * h[n] + Ba[n] * dx;
            y += Ca[n] * h[n];
        }
#pragma unroll
        for (int n = 0; n < 4; ++n) {
            float e = fast_exp2(dt * A2[n + 4]);
            h[n + 4] = e * h[n + 4] + Bb[n] * dx;
            y += Cb[n] * h[n + 4];
        }
#pragma unroll
        for (int n = 0; n < 4; ++n) {
            float e = fast_exp2(dt * A2[n + 8]);
            h[n + 8] = e * h[n + 8] + Bc[n] * dx;
            y += Cc[n] * h[n + 8];
        }
#pragma unroll
        for (int n = 0; n < 4; ++n) {
            float e = fast_exp2(dt * A2[n + 12]);
            h[n + 12] = e * h[n + 12] + Bd[n] * dx;
            y += Cd[n] * h[n + 12];
        }
        yp[(size_t)t * 2048] = (bf16)y;
    }
}

// ---------------------------------------------------------------------------
// launch.  Inputs: f32. Output: f32 (32 MiB).
// ws (>=64 MiB):
//   buf0 @0    (32Mi): xh -> delta -> y            (bf16)
//   buf1 @32Mi (32Mi): W_in_lo_b16 -> xc -> ry -> W_out_b16
// d_out (32 MiB) timeline:
//   @0      dtb bf16 (1Mi)            [reduce..gemm4]
//   @1Mi    BCf f32 (1Mi)             [reduce..scan_p3]
//   @2Mi    xb_1 (16Mi) [cvt..gemm1] -> Pbuf f32 (12Mi) [gemm3..reduce]
//           -> Hb bf16 (16Mi) [p1..p3] -> xb_2 (16Mi) [cvt..gemm6]
//   @18Mi   sdt f32 (2Mi)             [p1..p2]
//   @20Mi   Whi bf16 (4Mi)            [cvt_all..gemm6]
//   @24Mi   Wxb (384Ki) [..gemm3] | @24.5Mi Wdtb (256Ki) [..gemm4]
// gemm7 writes out over all of d_out (reads only ws).
// ---------------------------------------------------------------------------
extern "C" void kernel_launch(void* const* d_in, const int* in_sizes, int n_in,
                              void* d_out, int out_size, void* d_ws, size_t ws_size,
                              hipStream_t stream)
{
    const float* x      = (const float*)d_in[0];
    const float* W_in   = (const float*)d_in[1];
    const float* conv_w = (const float*)d_in[2];
    const float* conv_b = (const float*)d_in[3];
    const float* W_x    = (const float*)d_in[4];
    const float* W_dt   = (const float*)d_in[5];
    const float* b_dt   = (const float*)d_in[6];
    const float* A_raw  = (const float*)d_in[7];
    const float* Dvec   = (const float*)d_in[8];
    const float* W_out  = (const float*)d_in[9];
    float* out = (float*)d_out;

    char* ws = (char*)d_ws;
    bf16*  buf0   = (bf16*)(ws + 0);           // xh -> delta -> y
    bf16*  buf1   = (bf16*)(ws + 33554432);    // W_in_lo -> xc -> ry -> W_out
    char*  dob    = (char*)d_out;
    bf16*  dtb    = (bf16*)dob;                // dt cols, bf16 (1Mi)
    float* BCf    = (float*)(dob + 1048576);   // B/C cols, f32 (1Mi)
    bf16*  xb1    = (bf16*)(dob + 2097152);    // x bf16 (16Mi), until gemm1
    float* Pbuf   = (float*)(dob + 2097152);   // gemm3 partials (12Mi)
    bf16*  Hb     = (bf16*)(dob + 2097152);    // scan H bf16 (16Mi, NC=64)
    bf16*  xb2    = (bf16*)(dob + 2097152);    // x bf16 again, for gemm6
    float* sdtb   = (float*)(dob + 18874368);  // 2Mi
    bf16*  Whi    = (bf16*)(dob + 20971520);   // W_in_hi (4Mi)
    bf16*  Wxb    = (bf16*)(dob + 25165824);   // 384Ki
    bf16*  Wdtb   = (bf16*)(dob + 25690112);   // 256Ki
    bf16*  Wlo    = buf1;                       // W_in_lo (4Mi), pre-conv
    bf16*  Woutb  = buf1;                       // W_out (4Mi), post-gemm6

    // 0) merged one-time bf16 conversions (x, W_in lo+hi, W_x, W_dt)
    cvt_all<<<dim3(6304), 256, 0, stream>>>(
        x, W_in, W_x, W_dt, xb1, Wlo, Whi, Wxb, Wdtb);

    // 1) xh = x @ W_in[:2048]^T   M=8192 N=2048 K=1024  (256^2 8-phase)
    gemm256<0, bf16><<<dim3(32, 8), 512, 0, stream>>>(
        xb1, 1024, Wlo, 1024, buf0, 2048, 1024, nullptr);
    // 2) xc = silu(causal_conv(xh) + cb)
    conv_kernel<<<dim3(256, 4), 256, 0, stream>>>(buf0, conv_w, conv_b, buf1);
    // 3) dbc = xc @ W_x^T   M=8192 N=96 K=2048, split-K x4 -> f32 partials
    gemm_bt<0, float><<<dim3(64, 1, 4), 256, 0, stream>>>(
        buf1, 2048, Wxb, 2048, Pbuf, 96, 512, 96, nullptr, nullptr, 786432);
    reduce_split<<<dim3(768), 256, 0, stream>>>(Pbuf, dtb, BCf);
    // 4) delta = softplus(dt @ W_dt^T + b_dt)   (lda=64, K=64)
    gemm_bt<1, bf16><<<dim3(64, 16), 256, 0, stream>>>(
        dtb, 64, Wdtb, 64, buf0, 2048, 64, 2048, b_dt, nullptr, 0);
    // 5) chunk-parallel scan (NC=64) -> ry (ungated), in place over xc
    scan_p1<<<dim3(8, 4, 64), 256, 0, stream>>>(
        buf0, BCf, A_raw, buf1, Hb, sdtb);
    scan_p2<<<dim3(512), 256, 0, stream>>>(Hb, sdtb, A_raw);
    scan_p3<<<dim3(8, 4, 64), 256, 0, stream>>>(
        buf0, BCf, A_raw, Dvec, Hb, buf1, buf1);
    // 6) y = ry * silu(x @ W_in[2048:]^T)   (fused z-GEMM + gate, 256^2)
    cvt_bf16<<<dim3(4096), 256, 0, stream>>>(x, xb2, 1048576);
    gemm256<2, bf16><<<dim3(32, 8), 512, 0, stream>>>(
        xb2, 1024, Whi, 1024, buf0, 2048, 1024, buf1);
    // 7) out = y @ W_out^T  (f32 store)  M=8192 N=1024 K=2048
    cvt_bf16<<<dim3(1024), 256, 0, stream>>>(W_out, Woutb, 262144);
    gemm_bt<0, float><<<dim3(64, 8), 256, 0, stream>>>(
        buf0, 2048, Woutb, 2048, out, 1024, 2048, 1024, nullptr, nullptr, 0);
}

// Round 12
// 404.195 us; speedup vs baseline: 1.1048x; 1.1048x over previous
//
#include <hip/hip_runtime.h>
#include <hip/hip_bf16.h>

typedef __bf16 bf16;
typedef __bf16 bf16x4 __attribute__((ext_vector_type(4)));
typedef __bf16 bf16x8 __attribute__((ext_vector_type(8)));
typedef float f32x4 __attribute__((ext_vector_type(4)));

__device__ __forceinline__ float fast_exp2(float x) {
#if __has_builtin(__builtin_amdgcn_exp2f)
    return __builtin_amdgcn_exp2f(x);
#else
    return exp2f(x);
#endif
}

// fast natural log via v_log_f32 -- log1pf() lowers to the slow OCML path
// (~260 VALU inst/elem measured in r6's delta-GEMM; fix was -42 us).
__device__ __forceinline__ float fast_log(float x) {
#if __has_builtin(__builtin_amdgcn_logf)
    return __builtin_amdgcn_logf(x) * 0.6931471805599453f;
#else
    return __logf(x);
#endif
}

// async global->LDS, 16B per lane. lds base must be wave-uniform; the HW
// writes lds + lane*16; the GLOBAL address is per-lane. (m97 pattern)
__device__ __forceinline__ void gload16(bf16* lds, const bf16* g) {
    __builtin_amdgcn_global_load_lds(
        (const __attribute__((address_space(1))) void*)g,
        (__attribute__((address_space(3))) void*)lds,
        16, 0, 0);
}

// ---------------------------------------------------------------------------
// f32 -> bf16 vectorized cast (8 elems / thread)
// ---------------------------------------------------------------------------
__device__ __forceinline__ bf16x8 cvt8(const float* p) {
    float4 a = *(const float4*)p;
    float4 b = *(const float4*)(p + 4);
    bf16x8 r;
    r[0] = (bf16)a.x; r[1] = (bf16)a.y; r[2] = (bf16)a.z; r[3] = (bf16)a.w;
    r[4] = (bf16)b.x; r[5] = (bf16)b.y; r[6] = (bf16)b.z; r[7] = (bf16)b.w;
    return r;
}

__global__ __launch_bounds__(256) void cvt_bf16(
    const float* __restrict__ in, bf16* __restrict__ out, int n8)
{
    int i = blockIdx.x * 256 + threadIdx.x;
    if (i < n8)
        *(bf16x8*)(out + (size_t)i * 8) = cvt8(in + (size_t)i * 8);
}

// one merged pass for all start-of-graph conversions:
// x (1048576 x8), W_in lo (262144), W_in hi (262144), W_x (24576), W_dt (16384)
__global__ __launch_bounds__(256) void cvt_all(
    const float* __restrict__ x,  const float* __restrict__ W_in,
    const float* __restrict__ W_x, const float* __restrict__ W_dt,
    bf16* __restrict__ xb, bf16* __restrict__ Wlo, bf16* __restrict__ Whi,
    bf16* __restrict__ Wxb, bf16* __restrict__ Wdtb)
{
    int i = blockIdx.x * 256 + threadIdx.x;
    if (i < 1048576) {
        *(bf16x8*)(xb + (size_t)i * 8) = cvt8(x + (size_t)i * 8);
    } else if (i < 1310720) {
        int j = i - 1048576;
        *(bf16x8*)(Wlo + (size_t)j * 8) = cvt8(W_in + (size_t)j * 8);
    } else if (i < 1572864) {
        int j = i - 1310720;
        *(bf16x8*)(Whi + (size_t)j * 8) = cvt8(W_in + 2097152 + (size_t)j * 8);
    } else if (i < 1597440) {
        int j = i - 1572864;
        *(bf16x8*)(Wxb + (size_t)j * 8) = cvt8(W_x + (size_t)j * 8);
    } else if (i < 1613824) {
        int j = i - 1597440;
        *(bf16x8*)(Wdtb + (size_t)j * 8) = cvt8(W_dt + (size_t)j * 8);
    }
}

// ---------------------------------------------------------------------------
// 256x256 8-phase GEMM (T2+T3+T4+T5), XOR-swizzled LDS.
// r11 post-mortem: linear [256][64] LDS rows (128B stride) gave a 16-way
// bank conflict on every ds_read_b128 (18.9M conflicts, MfmaUtil 18.5%).
// Fix per rule #21 (both-sides-or-neither with global_load_lds):
//   - LDS DMA dest stays LINEAR (HW constraint: base + lane*16);
//   - the per-lane GLOBAL source column is pre-swizzled: 16B-slot
//     s' = s ^ (row&7)  (involution); write-side row&7 == lane>>3;
//   - ds_read applies the same XOR: slot (quad+ks*4) ^ (l16&7).
// Result: each quad's 16 lanes spread over all 8 slots (32 banks), 2
// lanes/slot = free (m136).  Same data -> same MFMA order -> absmax-neutral.
// 8 waves (2Mx4N), 512 thr, BK=64, LDS=128KB (1 block/CU).  Counted
// s_waitcnt vmcnt(2) + raw s_barrier at tile entry; barrier at tile exit;
// never vmcnt(0) in the loop.  Requires M%256==0, N%256==0, K%128==0.
// EPI==0: plain store   EPI==2: out = gmul[row,col] * silu(acc)
// ---------------------------------------------------------------------------
template <int EPI, typename TC>
__global__ __launch_bounds__(512, 2) void gemm256(
    const bf16* __restrict__ A, int lda,
    const bf16* __restrict__ B, int ldb,
    TC* __restrict__ C, int ldc,
    int K, const bf16* __restrict__ gmul)
{
    __shared__ bf16 sA[2][256 * 64];
    __shared__ bf16 sB[2][256 * 64];

    const int tid  = threadIdx.x;
    const int lane = tid & 63;
    const int wave = tid >> 6;      // 0..7
    const int quad = lane >> 4;
    const int l16  = lane & 15;
    const int wr   = wave >> 2;     // 0..1  (M half)
    const int wc   = wave & 3;      // 0..3  (N quarter)
    const int bm   = blockIdx.x << 8;
    const int bn   = blockIdx.y << 8;

    // staging map: unit u in {0:A-half0, 1:A-half1, 2:B-half0, 3:B-half1};
    // wave covers 16 rows of the 128-row half via 2 gload16 (8 rows each).
    // GLOBAL col is slot-swizzled: s' = (lane&7) ^ (lane>>3)  [row&7 = lane>>3]
    const int srow = wave * 16 + (lane >> 3);
    const int scol = (((lane & 7) ^ (lane >> 3)) << 3);

    f32x4 acc[8][4] = {};

    const int KT = K >> 6;

#define STAGE(pb, u, kt) do {                                              \
    int kc_ = (kt) * 64; if (kc_ > K - 64) kc_ = K - 64;                   \
    const int half_ = (u) & 1;                                             \
    bf16* dst_ = (((u) < 2) ? sA[pb] : sB[pb]) + (half_ * 128 + wave * 16) * 64; \
    const bf16* src_ = ((u) < 2)                                           \
        ? A + (size_t)(bm + half_ * 128 + srow) * lda + kc_ + scol         \
        : B + (size_t)(bn + half_ * 128 + srow) * ldb + kc_ + scol;        \
    const int ld_ = ((u) < 2) ? lda : ldb;                                 \
    gload16(dst_, src_);                                                   \
    gload16(dst_ + 8 * 64, src_ + (size_t)8 * ld_);                        \
} while (0)

    // prologue: tile 0 -> buf0 (8 loads/thread-wave)
    STAGE(0, 0, 0); STAGE(0, 1, 0); STAGE(0, 2, 0); STAGE(0, 3, 0);

    const int sw = l16 & 7;         // read-side swizzle (row&7, lane-const)

    for (int it = 0; it < KT / 2; ++it) {
#pragma unroll
        for (int ph = 0; ph < 8; ++ph) {
            const int p = ph >> 2;          // buffer being read
            const int q = ph & 3;           // phase-within-tile = quadrant
            // phases 0-3 stage tile 2it+1 -> buf1; 4-7 stage 2it+2 -> buf0
            STAGE(p ^ 1, q, 2 * it + 1 + p);
            if (q == 0) {
                // drain the tile we are about to read (2 newest stay in flight)
                asm volatile("s_waitcnt vmcnt(2)" ::: "memory");
                __builtin_amdgcn_s_barrier();
            }
            const int qm = q >> 1, qn = q & 1;
            bf16x8 af[4][2], bq[2][2];
#pragma unroll
            for (int fm = 0; fm < 4; ++fm)
#pragma unroll
                for (int ks = 0; ks < 2; ++ks)
                    af[fm][ks] = *(const bf16x8*)(sA[p]
                        + (wr * 128 + qm * 64 + fm * 16 + l16) * 64
                        + (((quad + ks * 4) ^ sw) << 3));
#pragma unroll
            for (int fn = 0; fn < 2; ++fn)
#pragma unroll
                for (int ks = 0; ks < 2; ++ks)
                    bq[fn][ks] = *(const bf16x8*)(sB[p]
                        + (wc * 64 + qn * 32 + fn * 16 + l16) * 64
                        + (((quad + ks * 4) ^ sw) << 3));
            __builtin_amdgcn_s_setprio(1);
#pragma unroll
            for (int fm = 0; fm < 4; ++fm)
#pragma unroll
                for (int fn = 0; fn < 2; ++fn)
#pragma unroll
                    for (int ks = 0; ks < 2; ++ks)
                        acc[qm * 4 + fm][qn * 2 + fn] =
                            __builtin_amdgcn_mfma_f32_16x16x32_bf16(
                                af[fm][ks], bq[fn][ks],
                                acc[qm * 4 + fm][qn * 2 + fn], 0, 0, 0);
            __builtin_amdgcn_s_setprio(0);
            if (q == 3) __builtin_amdgcn_s_barrier();  // buffer handoff
        }
    }
#undef STAGE

    // epilogue: C/D layout row = quad*4 + r, col = l16 (m89-verified)
#pragma unroll
    for (int mi = 0; mi < 8; ++mi) {
        const int row = bm + wr * 128 + mi * 16 + quad * 4;
#pragma unroll
        for (int ni = 0; ni < 4; ++ni) {
            const int col = bn + wc * 64 + ni * 16 + l16;
#pragma unroll
            for (int r = 0; r < 4; ++r) {
                float v = acc[mi][ni][r];
                if (EPI == 2) {
                    float g = v / (1.f + __expf(-v));   // silu(z)
                    v = (float)gmul[(size_t)(row + r) * ldc + col] * g;
                }
                C[(size_t)(row + r) * ldc + col] = (TC)v;
            }
        }
    }
}

// ---------------------------------------------------------------------------
// C[M x N] = A[M x K] * B[N x K]^T   (A,B bf16; f32 accum; TC out)
// m97 structure, BK=64 (used for the small/odd-shape GEMMs: N=96 splitK,
// K=64 delta, N=1024 out).
// EPI==0: plain   EPI==1: softplus(acc + bias_f32[col])
// EPI==2: out = gmul_bf16[row,col] * silu(acc)
// grid.z splits K: block z computes K range [z*K,(z+1)*K) -> C + z*zstride.
// Requires K % 64 == 0.
// ---------------------------------------------------------------------------
template <int EPI, typename TC>
__global__ __launch_bounds__(256, 2) void gemm_bt(
    const bf16* __restrict__ A, int lda,
    const bf16* __restrict__ B, int ldb,
    TC* __restrict__ C, int ldc,
    int K, int Neff, const float* __restrict__ bias,
    const bf16* __restrict__ gmul, size_t zstride)
{
    __shared__ bf16 As0[128 * 32];
    __shared__ bf16 As1[128 * 32];
    __shared__ bf16 Bs0[128 * 32];
    __shared__ bf16 Bs1[128 * 32];

    const int tid  = threadIdx.x;
    const int lane = tid & 63;
    const int wave = tid >> 6;
    const int quad = lane >> 4;
    const int l16  = lane & 15;
    const int wm   = (wave >> 1) << 6;
    const int wn   = (wave & 1) << 6;
    const int bm   = blockIdx.x << 7;
    const int bn   = blockIdx.y << 7;
    const int kb   = blockIdx.z * K;

    const int srow = (wave << 4) + (lane >> 2);
    const int scol = (lane & 3) << 3;

    const bf16* Ag0 = A + (size_t)(bm + srow) * lda + kb + scol;
    const bf16* Ag1 = Ag0 + (size_t)lda * 64;
    int br0 = bn + srow;      br0 = br0 < Neff ? br0 : Neff - 1;
    int br1 = bn + srow + 64; br1 = br1 < Neff ? br1 : Neff - 1;
    const bf16* Bg0 = B + (size_t)br0 * ldb + kb + scol;
    const bf16* Bg1 = B + (size_t)br1 * ldb + kb + scol;

    const int wofs = wave * 512;            // wave-uniform LDS base offset

    f32x4 acc[4][4] = {};

    for (int k0 = 0; k0 < K; k0 += 64) {
        if (k0) __syncthreads();            // protect LDS from overwrite
        gload16(As0 + wofs,        Ag0 + k0);
        gload16(As0 + 2048 + wofs, Ag1 + k0);
        gload16(Bs0 + wofs,        Bg0 + k0);
        gload16(Bs0 + 2048 + wofs, Bg1 + k0);
        gload16(As1 + wofs,        Ag0 + k0 + 32);
        gload16(As1 + 2048 + wofs, Ag1 + k0 + 32);
        gload16(Bs1 + wofs,        Bg0 + k0 + 32);
        gload16(Bs1 + 2048 + wofs, Bg1 + k0 + 32);
        __syncthreads();                    // drains vmcnt before barrier

#pragma unroll
        for (int kk = 0; kk < 2; ++kk) {
            const bf16* Ak = kk ? As1 : As0;
            const bf16* Bk = kk ? Bs1 : Bs0;
            bf16x8 af[4], bfr[4];
#pragma unroll
            for (int i = 0; i < 4; ++i) {
                af[i]  = *(const bf16x8*)(Ak + (wm + i * 16 + l16) * 32 + quad * 8);
                bfr[i] = *(const bf16x8*)(Bk + (wn + i * 16 + l16) * 32 + quad * 8);
            }
#pragma unroll
            for (int mi = 0; mi < 4; ++mi)
#pragma unroll
                for (int ni = 0; ni < 4; ++ni)
                    acc[mi][ni] = __builtin_amdgcn_mfma_f32_16x16x32_bf16(
                        af[mi], bfr[ni], acc[mi][ni], 0, 0, 0);
        }
    }

    TC* Cz = C + (size_t)blockIdx.z * zstride;

    // C/D layout: row = quad*4 + r, col = l16  (m89-verified)
#pragma unroll
    for (int mi = 0; mi < 4; ++mi) {
        const int row = bm + wm + mi * 16 + quad * 4;
#pragma unroll
        for (int ni = 0; ni < 4; ++ni) {
            const int col = bn + wn + ni * 16 + l16;
            if (col < Neff) {
                float bc = (EPI == 1) ? bias[col] : 0.f;
#pragma unroll
                for (int r = 0; r < 4; ++r) {
                    float v = acc[mi][ni][r];
                    if (EPI == 1) {
                        v += bc;
                        float sp = fast_log(1.f + __expf(v));
                        v = (v > 15.f) ? v : sp;
                    } else if (EPI == 2) {
                        float g = v / (1.f + __expf(-v));   // silu(z)
                        v = (float)gmul[(size_t)(row + r) * ldc + col] * g;
                    }
                    Cz[(size_t)(row + r) * ldc + col] = (TC)v;
                }
            }
        }
    }
}

// ---------------------------------------------------------------------------
// split-K reduce + dtype split: row-major [8192][96] f32 partials summed
// over 4 z-slices.  Cols 0-63 (dt) -> dtb bf16 (gemm4 MFMA operand);
// cols 64-95 (B,C) -> BCf f32 (scan reads f32 directly).
// ---------------------------------------------------------------------------
__global__ __launch_bounds__(256) void reduce_split(
    const float* __restrict__ P, bf16* __restrict__ dtb,
    float* __restrict__ BCf)
{
    const size_t base = ((size_t)blockIdx.x * 256 + threadIdx.x) * 4;
    f32x4 s = *(const f32x4*)(P + base);
#pragma unroll
    for (int z = 1; z < 4; ++z) {
        f32x4 p = *(const f32x4*)(P + (size_t)z * 786432 + base);
        s[0] += p[0]; s[1] += p[1]; s[2] += p[2]; s[3] += p[3];
    }
    const int row = (int)(base / 96);
    const int col = (int)(base % 96);
    if (col < 64) {
        bf16x4 o;
        o[0] = (bf16)s[0]; o[1] = (bf16)s[1];
        o[2] = (bf16)s[2]; o[3] = (bf16)s[3];
        *(bf16x4*)(dtb + (size_t)row * 64 + col) = o;
    } else {
        *(f32x4*)(BCf + (size_t)row * 32 + (col - 64)) = s;
    }
}

// ---------------------------------------------------------------------------
// causal depthwise conv (k=4, left pad 3) + bias + SiLU: xh bf16 -> xc bf16
// t-tiled: each thread produces 8 consecutive t for 8 channels.
// ---------------------------------------------------------------------------
__global__ __launch_bounds__(256) void conv_kernel(
    const bf16* __restrict__ xh, const float* __restrict__ cw,
    const float* __restrict__ cb, bf16* __restrict__ xc)
{
    const int t0 = blockIdx.x << 3;          // 0..2040
    const int b  = blockIdx.y;
    const int d  = threadIdx.x * 8;

    float4 wv[8];           // wv[i] = taps 0..3 of channel d+i
#pragma unroll
    for (int i = 0; i < 8; ++i)
        wv[i] = *(const float4*)(cw + (d + i) * 4);

    float4 cb0 = *(const float4*)(cb + d);
    float4 cb1 = *(const float4*)(cb + d + 4);

    float acc[8][8];
#pragma unroll
    for (int k = 0; k < 8; ++k) {
        acc[k][0] = cb0.x; acc[k][1] = cb0.y; acc[k][2] = cb0.z; acc[k][3] = cb0.w;
        acc[k][4] = cb1.x; acc[k][5] = cb1.y; acc[k][6] = cb1.z; acc[k][7] = cb1.w;
    }

    const bf16* base = xh + ((size_t)b * 2048 + t0) * 2048 + d;

#pragma unroll
    for (int r = 0; r < 11; ++r) {
        const int t_in = t0 - 3 + r;
        if (t_in >= 0) {                     // uniform branch
            bf16x8 v = *(const bf16x8*)(base + (size_t)(r - 3) * 2048);
            float vf[8];
#pragma unroll
            for (int i = 0; i < 8; ++i) vf[i] = (float)v[i];
#pragma unroll
            for (int j = 0; j < 4; ++j) {    // tap j multiplies x[t-3+j]
                const int local = r - j;     // output index t0+local
                if (local >= 0 && local < 8) {
#pragma unroll
                    for (int i = 0; i < 8; ++i) {
                        float w = (j == 0) ? wv[i].x : (j == 1) ? wv[i].y
                                : (j == 2) ? wv[i].z : wv[i].w;
                        acc[local][i] += w * vf[i];
                    }
                }
            }
        }
    }

    bf16* ob = xc + ((size_t)b * 2048 + t0) * 2048 + d;
#pragma unroll
    for (int k = 0; k < 8; ++k) {
        bf16x8 o;
#pragma unroll
        for (int i = 0; i < 8; ++i) {
            float s = acc[k][i];
            o[i] = (bf16)(s / (1.f + __expf(-s)));
        }
        *(bf16x8*)(ob + (size_t)k * 2048) = o;
    }
}

// ---------------------------------------------------------------------------
// Chunk-parallel selective scan, NC=64 chunks x TC=32 t.
// thread = (b, c, d); 16 states in registers; B/C read as f32x4.
// BCf layout: [row][32] f32, idx 0-15 = B[n], 16-31 = C[n].
// Hb: (b, c, d, n) bf16.  sdt: (b, c, d) f32; p2 recomputes A_c.
// ---------------------------------------------------------------------------
__global__ __launch_bounds__(256, 4) void scan_p1(
    const bf16* __restrict__ delta, const float* __restrict__ BCf,
    const float* __restrict__ A_raw, const bf16* __restrict__ xc,
    bf16* __restrict__ Hb, float* __restrict__ sdtb)
{
    const int d = (blockIdx.x << 8) + threadIdx.x;
    const int b = blockIdx.y;
    const int c = blockIdx.z;

    float A2[16];           // A[n] * log2(e)
#pragma unroll
    for (int n = 0; n < 16; ++n)
        A2[n] = -__expf(A_raw[n * 2048 + d]) * 1.44269504f;

    float h[16];
#pragma unroll
    for (int n = 0; n < 16; ++n) h[n] = 0.f;
    float sdt = 0.f;

    const size_t xbase = ((size_t)(b * 2048 + c * 32)) * 2048 + d;
    const bf16* xp = xc + xbase;
    const bf16* dp = delta + xbase;
    const float* bp = BCf + (size_t)(b * 2048 + c * 32) * 32;

    bf16 xr = xp[0], dr = dp[0];
    f32x4 B0 = *(const f32x4*)(bp);
    f32x4 B1 = *(const f32x4*)(bp + 4);
    f32x4 B2 = *(const f32x4*)(bp + 8);
    f32x4 B3 = *(const f32x4*)(bp + 12);

#pragma unroll 4
    for (int t = 0; t < 32; ++t) {
        const float x  = (float)xr;
        const float dt = (float)dr;
        const f32x4 Ba = B0, Bb = B1, Bc = B2, Bd = B3;
        if (t < 31) {
            xr = xp[(size_t)(t + 1) * 2048];
            dr = dp[(size_t)(t + 1) * 2048];
            const float* nb = bp + (size_t)(t + 1) * 32;
            B0 = *(const f32x4*)nb;
            B1 = *(const f32x4*)(nb + 4);
            B2 = *(const f32x4*)(nb + 8);
            B3 = *(const f32x4*)(nb + 12);
        }
        const float dx = dt * x;
        sdt += dt;
#pragma unroll
        for (int n = 0; n < 4; ++n) {
            float e = fast_exp2(dt * A2[n]);
            h[n] = e * h[n] + Ba[n] * dx;
        }
#pragma unroll
        for (int n = 0; n < 4; ++n) {
            float e = fast_exp2(dt * A2[n + 4]);
            h[n + 4] = e * h[n + 4] + Bb[n] * dx;
        }
#pragma unroll
        for (int n = 0; n < 4; ++n) {
            float e = fast_exp2(dt * A2[n + 8]);
            h[n + 8] = e * h[n + 8] + Bc[n] * dx;
        }
#pragma unroll
        for (int n = 0; n < 4; ++n) {
            float e = fast_exp2(dt * A2[n + 12]);
            h[n + 12] = e * h[n + 12] + Bd[n] * dx;
        }
    }

    const size_t hbase = (((size_t)b * 64 + c) * 2048 + d) * 16;
    bf16x8 h0, h1;
#pragma unroll
    for (int n = 0; n < 8; ++n) {
        h0[n] = (bf16)h[n];
        h1[n] = (bf16)h[n + 8];
    }
    *(bf16x8*)(Hb + hbase) = h0;
    *(bf16x8*)(Hb + hbase + 8) = h1;
    sdtb[((size_t)b * 64 + c) * 2048 + d] = sdt;
}

// sequential combine over 64 chunks; recomputes A_c = exp2(A2 * sdt_c).
// thread id = b*32768 + d*16 + n  (H reads/writes coalesced).
__global__ __launch_bounds__(256) void scan_p2(
    bf16* __restrict__ Hb, const float* __restrict__ sdtb,
    const float* __restrict__ A_raw)
{
    const int id  = blockIdx.x * 256 + threadIdx.x;
    const int b   = id >> 15;
    const int rem = id & 32767;
    const int d   = rem >> 4;
    const int n   = rem & 15;

    const float A2 = -__expf(A_raw[n * 2048 + d]) * 1.44269504f;
    const size_t hb = (size_t)b * 64 * 32768 + rem;   // + c*32768
    const size_t sb = (size_t)b * 64 * 2048 + d;      // + c*2048

    float ht = (float)Hb[hb];              // H~_0 = H_0 (already stored)
#pragma unroll 4
    for (int c = 1; c < 64; ++c) {
        float Hv = (float)Hb[hb + (size_t)c * 32768];
        float a  = fast_exp2(A2 * sdtb[sb + (size_t)c * 2048]);
        ht = Hv + a * ht;
        Hb[hb + (size_t)c * 32768] = (bf16)ht;
    }
}

__global__ __launch_bounds__(256, 4) void scan_p3(
    const bf16* __restrict__ delta, const float* __restrict__ BCf,
    const float* __restrict__ A_raw, const float* __restrict__ Dvec,
    const bf16* __restrict__ Hb, const bf16* xc, bf16* ry)
{
    const int d = (blockIdx.x << 8) + threadIdx.x;
    const int b = blockIdx.y;
    const int c = blockIdx.z;

    float A2[16];
#pragma unroll
    for (int n = 0; n < 16; ++n)
        A2[n] = -__expf(A_raw[n * 2048 + d]) * 1.44269504f;
    const float Dd = Dvec[d];

    float h[16];
    if (c > 0) {
        const bf16* Hp = Hb + (((size_t)b * 64 + (c - 1)) * 2048 + d) * 16;
        bf16x8 v0 = *(const bf16x8*)Hp;
        bf16x8 v1 = *(const bf16x8*)(Hp + 8);
#pragma unroll
        for (int n = 0; n < 8; ++n) {
            h[n]     = (float)v0[n];
            h[n + 8] = (float)v1[n];
        }
    } else {
#pragma unroll
        for (int n = 0; n < 16; ++n) h[n] = 0.f;
    }

    const size_t xbase = ((size_t)(b * 2048 + c * 32)) * 2048 + d;
    const bf16* xp = xc + xbase;
    const bf16* dp = delta + xbase;
    const float* bp = BCf + (size_t)(b * 2048 + c * 32) * 32;
    bf16* yp = ry + xbase;

    bf16 xr = xp[0], dr = dp[0];
    f32x4 B0 = *(const f32x4*)(bp);
    f32x4 B1 = *(const f32x4*)(bp + 4);
    f32x4 B2 = *(const f32x4*)(bp + 8);
    f32x4 B3 = *(const f32x4*)(bp + 12);
    f32x4 C0 = *(const f32x4*)(bp + 16);
    f32x4 C1 = *(const f32x4*)(bp + 20);
    f32x4 C2 = *(const f32x4*)(bp + 24);
    f32x4 C3 = *(const f32x4*)(bp + 28);

#pragma unroll 4
    for (int t = 0; t < 32; ++t) {
        const float x  = (float)xr;
        const float dt = (float)dr;
        const f32x4 Ba = B0, Bb = B1, Bc = B2, Bd = B3;
        const f32x4 Ca = C0, Cb = C1, Cc = C2, Cd = C3;
        if (t < 31) {
            xr = xp[(size_t)(t + 1) * 2048];
            dr = dp[(size_t)(t + 1) * 2048];
            const float* nb = bp + (size_t)(t + 1) * 32;
            B0 = *(const f32x4*)nb;
            B1 = *(const f32x4*)(nb + 4);
            B2 = *(const f32x4*)(nb + 8);
            B3 = *(const f32x4*)(nb + 12);
            C0 = *(const f32x4*)(nb + 16);
            C1 = *(const f32x4*)(nb + 20);
            C2 = *(const f32x4*)(nb + 24);
            C3 = *(const f32x4*)(nb + 28);
        }
        const float dx = dt * x;
        float y = Dd * x;
#pragma unroll
        for (int n = 0; n < 4; ++n) {
            float e = fast_exp2(dt * A2[n]);
            h[n] = e * h[n] + Ba[n] * dx;
            y += Ca[n] * h[n];
        }
#pragma unroll
        for (int n = 0; n < 4; ++n) {
            float e = fast_exp2(dt * A2[n + 4]);
            h[n + 4] = e * h[n + 4] + Bb[n] * dx;
            y += Cb[n] * h[n + 4];
        }
#pragma unroll
        for (int n = 0; n < 4; ++n) {
            float e = fast_exp2(dt * A2[n + 8]);
            h[n + 8] = e * h[n + 8] + Bc[n] * dx;
            y += Cc[n] * h[n + 8];
        }
#pragma unroll
        for (int n = 0; n < 4; ++n) {
            float e = fast_exp2(dt * A2[n + 12]);
            h[n + 12] = e * h[n + 12] + Bd[n] * dx;
            y += Cd[n] * h[n + 12];
        }
        yp[(size_t)t * 2048] = (bf16)y;
    }
}

// ---------------------------------------------------------------------------
// launch.  Inputs: f32. Output: f32 (32 MiB).
// ws (>=64 MiB):
//   buf0 @0    (32Mi): xh -> delta -> y            (bf16)
//   buf1 @32Mi (32Mi): W_in_lo_b16 -> xc -> ry -> W_out_b16
// d_out (32 MiB) timeline:
//   @0      dtb bf16 (1Mi)            [reduce..gemm4]
//   @1Mi    BCf f32 (1Mi)             [reduce..scan_p3]
//   @2Mi    xb_1 (16Mi) [cvt..gemm1] -> Pbuf f32 (12Mi) [gemm3..reduce]
//           -> Hb bf16 (16Mi) [p1..p3] -> xb_2 (16Mi) [cvt..gemm6]
//   @18Mi   sdt f32 (2Mi)             [p1..p2]
//   @20Mi   Whi bf16 (4Mi)            [cvt_all..gemm6]
//   @24Mi   Wxb (384Ki) [..gemm3] | @24.5Mi Wdtb (256Ki) [..gemm4]
// gemm7 writes out over all of d_out (reads only ws).
// ---------------------------------------------------------------------------
extern "C" void kernel_launch(void* const* d_in, const int* in_sizes, int n_in,
                              void* d_out, int out_size, void* d_ws, size_t ws_size,
                              hipStream_t stream)
{
    const float* x      = (const float*)d_in[0];
    const float* W_in   = (const float*)d_in[1];
    const float* conv_w = (const float*)d_in[2];
    const float* conv_b = (const float*)d_in[3];
    const float* W_x    = (const float*)d_in[4];
    const float* W_dt   = (const float*)d_in[5];
    const float* b_dt   = (const float*)d_in[6];
    const float* A_raw  = (const float*)d_in[7];
    const float* Dvec   = (const float*)d_in[8];
    const float* W_out  = (const float*)d_in[9];
    float* out = (float*)d_out;

    char* ws = (char*)d_ws;
    bf16*  buf0   = (bf16*)(ws + 0);           // xh -> delta -> y
    bf16*  buf1   = (bf16*)(ws + 33554432);    // W_in_lo -> xc -> ry -> W_out
    char*  dob    = (char*)d_out;
    bf16*  dtb    = (bf16*)dob;                // dt cols, bf16 (1Mi)
    float* BCf    = (float*)(dob + 1048576);   // B/C cols, f32 (1Mi)
    bf16*  xb1    = (bf16*)(dob + 2097152);    // x bf16 (16Mi), until gemm1
    float* Pbuf   = (float*)(dob + 2097152);   // gemm3 partials (12Mi)
    bf16*  Hb     = (bf16*)(dob + 2097152);    // scan H bf16 (16Mi, NC=64)
    bf16*  xb2    = (bf16*)(dob + 2097152);    // x bf16 again, for gemm6
    float* sdtb   = (float*)(dob + 18874368);  // 2Mi
    bf16*  Whi    = (bf16*)(dob + 20971520);   // W_in_hi (4Mi)
    bf16*  Wxb    = (bf16*)(dob + 25165824);   // 384Ki
    bf16*  Wdtb   = (bf16*)(dob + 25690112);   // 256Ki
    bf16*  Wlo    = buf1;                       // W_in_lo (4Mi), pre-conv
    bf16*  Woutb  = buf1;                       // W_out (4Mi), post-gemm6

    // 0) merged one-time bf16 conversions (x, W_in lo+hi, W_x, W_dt)
    cvt_all<<<dim3(6304), 256, 0, stream>>>(
        x, W_in, W_x, W_dt, xb1, Wlo, Whi, Wxb, Wdtb);

    // 1) xh = x @ W_in[:2048]^T   M=8192 N=2048 K=1024  (256^2 8-phase)
    gemm256<0, bf16><<<dim3(32, 8), 512, 0, stream>>>(
        xb1, 1024, Wlo, 1024, buf0, 2048, 1024, nullptr);
    // 2) xc = silu(causal_conv(xh) + cb)
    conv_kernel<<<dim3(256, 4), 256, 0, stream>>>(buf0, conv_w, conv_b, buf1);
    // 3) dbc = xc @ W_x^T   M=8192 N=96 K=2048, split-K x4 -> f32 partials
    gemm_bt<0, float><<<dim3(64, 1, 4), 256, 0, stream>>>(
        buf1, 2048, Wxb, 2048, Pbuf, 96, 512, 96, nullptr, nullptr, 786432);
    reduce_split<<<dim3(768), 256, 0, stream>>>(Pbuf, dtb, BCf);
    // 4) delta = softplus(dt @ W_dt^T + b_dt)   (lda=64, K=64)
    gemm_bt<1, bf16><<<dim3(64, 16), 256, 0, stream>>>(
        dtb, 64, Wdtb, 64, buf0, 2048, 64, 2048, b_dt, nullptr, 0);
    // 5) chunk-parallel scan (NC=64) -> ry (ungated), in place over xc
    scan_p1<<<dim3(8, 4, 64), 256, 0, stream>>>(
        buf0, BCf, A_raw, buf1, Hb, sdtb);
    scan_p2<<<dim3(512), 256, 0, stream>>>(Hb, sdtb, A_raw);
    scan_p3<<<dim3(8, 4, 64), 256, 0, stream>>>(
        buf0, BCf, A_raw, Dvec, Hb, buf1, buf1);
    // 6) y = ry * silu(x @ W_in[2048:]^T)   (fused z-GEMM + gate, 256^2)
    cvt_bf16<<<dim3(4096), 256, 0, stream>>>(x, xb2, 1048576);
    gemm256<2, bf16><<<dim3(32, 8), 512, 0, stream>>>(
        xb2, 1024, Whi, 1024, buf0, 2048, 1024, buf1);
    // 7) out = y @ W_out^T  (f32 store)  M=8192 N=1024 K=2048
    cvt_bf16<<<dim3(1024), 256, 0, stream>>>(W_out, Woutb, 262144);
    gemm_bt<0, float><<<dim3(64, 8), 256, 0, stream>>>(
        buf0, 2048, Woutb, 2048, out, 1024, 2048, 1024, nullptr, nullptr, 0);
}